// Round 1
// baseline (259.810 us; speedup 1.0000x reference)
//
#include <hip/hip_runtime.h>
#include <math.h>

#define HH 256
#define WW 256
#define VV 192
#define DD 256
#define SS 256

// geometry constants (match reference: linspace(-sqrt2, sqrt2, 256) spacing, DT = 2*sqrt2/256)
#define DSQ2      1.41421356237309504880
#define F_SQ2     ((float)DSQ2)
#define F_DS      ((float)(2.0 * DSQ2 / 255.0))          // index spacing in world units
#define F_DT      ((float)(2.0 * DSQ2 / 256.0))          // integration weight
#define F_INV_DS  ((float)(255.0 / (2.0 * DSQ2)))
#define F_SIG     ((float)(256.0 * DSQ2 / 255.0))        // pixels per index step (128*F_DS)

static __device__ __forceinline__ float view_angle(int v) {
    // matches np.linspace(0, pi, 192, endpoint=False) computed in f64 then cast to f32
    return (float)((double)v * (3.14159265358979323846 / 192.0));
}

// Kernel A: ray-driven forward projection + residual.
// One block per (b, v); one thread per detector d; loop over S samples.
// temp[b,v,d] = DT * sum_t bilerp(img_b, xp, yp) - proj[b,v,d]
__global__ __launch_bounds__(256)
void fwd_residual_kernel(const float* __restrict__ img_all,
                         const float* __restrict__ proj,
                         float* __restrict__ temp) {
    const int bv = blockIdx.x;              // 0 .. nb*VV-1
    const int b  = bv / VV;
    const int v  = bv - b * VV;
    const int d  = threadIdx.x;
    const float* __restrict__ img = img_all + b * (HH * WW);

    float sn, cs;
    sincosf(view_angle(v), &sn, &cs);

    const float s = fmaf((float)d, F_DS, -F_SQ2);
    // sample i: t = -sqrt2 + i*F_DS
    // xw = -s*sn + t*cs ; yw = s*cs + t*sn
    // xp = (xw+1)*128 - 0.5 ; yp = (yw+1)*128 - 0.5
    const float xw0 = fmaf(-s, sn, -F_SQ2 * cs);
    const float yw0 = fmaf( s, cs, -F_SQ2 * sn);
    const float x0  = fmaf(xw0, 128.0f, 127.5f);
    const float y0  = fmaf(yw0, 128.0f, 127.5f);
    const float xs  = cs * (F_DS * 128.0f);
    const float ys  = sn * (F_DS * 128.0f);

    float sum = 0.0f;
#pragma unroll 4
    for (int i = 0; i < SS; ++i) {
        const float xp = fmaf((float)i, xs, x0);
        const float yp = fmaf((float)i, ys, y0);
        const float xf = floorf(xp);
        const float yf = floorf(yp);
        const int ix = (int)xf;
        const int iy = (int)yf;
        const float fx = xp - xf;
        const float fy = yp - yf;
        const bool okx0 = ((unsigned)ix      < (unsigned)WW);
        const bool okx1 = ((unsigned)(ix + 1) < (unsigned)WW);
        const bool oky0 = ((unsigned)iy      < (unsigned)HH);
        const bool oky1 = ((unsigned)(iy + 1) < (unsigned)HH);
        const float* row0 = img + iy * WW;
        const float* row1 = row0 + WW;
        const float v00 = (okx0 && oky0) ? row0[ix]     : 0.0f;
        const float v10 = (okx1 && oky0) ? row0[ix + 1] : 0.0f;
        const float v01 = (okx0 && oky1) ? row1[ix]     : 0.0f;
        const float v11 = (okx1 && oky1) ? row1[ix + 1] : 0.0f;
        const float gx0 = 1.0f - fx;
        const float gy0 = 1.0f - fy;
        sum += (v00 * gx0 + v10 * fx) * gy0 + (v01 * gx0 + v11 * fx) * fy;
    }

    temp[bv * DD + d] = fmaf(F_DT, sum, -proj[bv * DD + d]);
}

// Kernel B: pixel-driven exact adjoint + update.
// For each pixel, back-rotate to continuous (d_c, t_c) index coords; the 2x2
// nearest samples are the ONLY ones with nonzero bilinear adjoint weight
// (|delta| <= sqrt2/sigma = 0.9961 < 1). Accumulate w * temp[v,d] over views.
__global__ __launch_bounds__(256)
void bwd_update_kernel(const float* __restrict__ input,
                       const float* __restrict__ temp,
                       const float* __restrict__ weight,
                       float* __restrict__ out) {
    __shared__ float s_cs[VV];
    __shared__ float s_sn[VV];
    const int tid = threadIdx.x;
    if (tid < VV) {
        float sn, cs;
        sincosf(view_angle(tid), &sn, &cs);
        s_cs[tid] = cs;
        s_sn[tid] = sn;
    }
    __syncthreads();

    const int idx = blockIdx.x * 256 + tid;
    const int b = idx >> 16;            // H*W = 65536 pixels per image
    const int y = (idx >> 8) & 255;
    const int x = idx & 255;
    const float* __restrict__ tb = temp + b * (VV * DD);

    const float xw = (x + 0.5f) * (1.0f / 128.0f) - 1.0f;
    const float yw = (y + 0.5f) * (1.0f / 128.0f) - 1.0f;

    float acc = 0.0f;
    for (int v = 0; v < VV; ++v) {
        const float cs = s_cs[v];
        const float sn = s_sn[v];
        // inverse rotation (M is symmetric orthogonal, M^-1 = M)
        const float sw = fmaf(-xw, sn, yw * cs);
        const float tw = fmaf( xw, cs, yw * sn);
        const float dc = (sw + F_SQ2) * F_INV_DS;
        const float tc = (tw + F_SQ2) * F_INV_DS;
        const float d0f = floorf(dc);
        const float t0f = floorf(tc);
        const int d0 = (int)d0f;
        const int t0 = (int)t0f;
        const float fd = dc - d0f;
        const float ft = tc - t0f;

        const float dd0 = -fd,  dd1 = 1.0f - fd;
        const float dt0 = -ft,  dt1 = 1.0f - ft;
        const bool okt0 = ((unsigned)t0       < (unsigned)SS);
        const bool okt1 = ((unsigned)(t0 + 1) < (unsigned)SS);

        // candidate d0
        if ((unsigned)d0 < (unsigned)DD) {
            float ws = 0.0f;
            if (okt0) {
                const float dx = F_SIG * fmaf(cs, dt0, -sn * dd0);
                const float dy = F_SIG * fmaf(cs, dd0,  sn * dt0);
                ws += fmaxf(0.0f, 1.0f - fabsf(dx)) * fmaxf(0.0f, 1.0f - fabsf(dy));
            }
            if (okt1) {
                const float dx = F_SIG * fmaf(cs, dt1, -sn * dd0);
                const float dy = F_SIG * fmaf(cs, dd0,  sn * dt1);
                ws += fmaxf(0.0f, 1.0f - fabsf(dx)) * fmaxf(0.0f, 1.0f - fabsf(dy));
            }
            acc = fmaf(ws, tb[v * DD + d0], acc);
        }
        // candidate d0+1
        if ((unsigned)(d0 + 1) < (unsigned)DD) {
            float ws = 0.0f;
            if (okt0) {
                const float dx = F_SIG * fmaf(cs, dt0, -sn * dd1);
                const float dy = F_SIG * fmaf(cs, dd1,  sn * dt0);
                ws += fmaxf(0.0f, 1.0f - fabsf(dx)) * fmaxf(0.0f, 1.0f - fabsf(dy));
            }
            if (okt1) {
                const float dx = F_SIG * fmaf(cs, dt1, -sn * dd1);
                const float dy = F_SIG * fmaf(cs, dd1,  sn * dt1);
                ws += fmaxf(0.0f, 1.0f - fabsf(dx)) * fmaxf(0.0f, 1.0f - fabsf(dy));
            }
            acc = fmaf(ws, tb[v * DD + d0 + 1], acc);
        }
    }

    out[idx] = fmaf(-weight[0] * F_DT, acc, input[idx]);
}

extern "C" void kernel_launch(void* const* d_in, const int* in_sizes, int n_in,
                              void* d_out, int out_size, void* d_ws, size_t ws_size,
                              hipStream_t stream) {
    const float* input  = (const float*)d_in[0];   // [nb, H, W]
    const float* proj   = (const float*)d_in[1];   // [nb, V, D]
    const float* weight = (const float*)d_in[2];   // [1]
    float* out  = (float*)d_out;                   // [nb, H, W]
    float* temp = (float*)d_ws;                    // [nb, V, D] residual sinogram

    const int nb = in_sizes[0] / (HH * WW);        // B*C = 2

    fwd_residual_kernel<<<nb * VV, 256, 0, stream>>>(input, proj, temp);
    bwd_update_kernel<<<(nb * HH * WW) / 256, 256, 0, stream>>>(input, temp, weight, out);
}

// Round 2
// 158.660 us; speedup vs baseline: 1.6375x; 1.6375x over previous
//
#include <hip/hip_runtime.h>
#include <math.h>

#define HH 256
#define WW 256
#define VV 192
#define DD 256
#define SS 256

// geometry constants (match reference: linspace(-sqrt2, sqrt2, 256) spacing, DT = 2*sqrt2/256)
#define DSQ2      1.41421356237309504880
#define F_SQ2     ((float)DSQ2)
#define F_DS      ((float)(2.0 * DSQ2 / 255.0))          // index spacing in world units
#define F_DT      ((float)(2.0 * DSQ2 / 256.0))          // integration weight
#define F_INV_DS  ((float)(255.0 / (2.0 * DSQ2)))
#define F_SIG     ((float)(256.0 * DSQ2 / 255.0))        // pixels per index step (128*F_DS)
#define F_RAD     ((float)(128.0 * DSQ2))                // 181.0193

static __device__ __forceinline__ float view_angle(int v) {
    // matches np.linspace(0, pi, 192, endpoint=False): f64 mul then cast
    return (float)((double)v * (3.14159265358979323846 / 192.0));
}

// ---------------------------------------------------------------------------
// Kernel A: ray-driven forward projection + residual, 2D-tiled gathers.
// Grid: (16 d-blocks, V views, nb images). Block: 256 threads = 16 d x 16 t-phases.
// Each thread sums 16 samples (t = tph + 16*j); LDS-reduce over the 16 phases.
// Lane mapping per view: the 16-wide lane dimension is assigned to whichever
// index (t or d) steps mostly along x, so a wave's 64 gather addresses span
// few image rows (few cache lines) at every angle.
// temp[b,v,d] = DT * sum_t bilerp(img_b, xp, yp) - proj[b,v,d]
// ---------------------------------------------------------------------------
__global__ __launch_bounds__(256)
void fwd_residual_kernel(const float* __restrict__ img_all,
                         const float* __restrict__ proj,
                         float* __restrict__ temp) {
    const int dblk = blockIdx.x;            // 0..15 (16 detectors each)
    const int v    = blockIdx.y;
    const int b    = blockIdx.z;
    const float* __restrict__ img = img_all + b * (HH * WW);

    float sn, cs;
    sincosf(view_angle(v), &sn, &cs);
    const bool tfast = (fabsf(cs) >= fabsf(sn));   // t-steps mostly along x?

    const int tid = threadIdx.x;
    const int wv = tid >> 6;
    const int ln = tid & 63;
    const int f  = ln & 15;                 // 16-wide (contiguous-lane) dim
    const int sl = ln >> 4;                 // 4-wide dim
    const int dl  = tfast ? ((wv << 2) | sl) : f;
    const int tph = tfast ? f : ((wv << 2) | sl);
    const int d = (dblk << 4) + dl;

    // pixel-space steps per index
    const float Xd = -sn * F_SIG, Yd = cs * F_SIG;   // per detector index
    const float Xt =  cs * F_SIG, Yt = sn * F_SIG;   // per t-sample index
    const float X0 = 127.5f - F_RAD * (cs - sn);     // sample (d=0, t=0)
    const float Y0 = 127.5f - F_RAD * (cs + sn);

    const float xb = fmaf((float)tph, Xt, fmaf((float)d, Xd, X0));
    const float yb = fmaf((float)tph, Yt, fmaf((float)d, Yd, Y0));
    const float Xs = 16.0f * Xt, Ys = 16.0f * Yt;

    float sum = 0.0f;
#pragma unroll 4
    for (int j = 0; j < 16; ++j) {
        const float xp = fmaf((float)j, Xs, xb);
        const float yp = fmaf((float)j, Ys, yb);
        const float xf = floorf(xp);
        const float yf = floorf(yp);
        const int ix = (int)xf;
        const int iy = (int)yf;
        const float fx = xp - xf;
        const float fy = yp - yf;
        const bool okx0 = ((unsigned)ix       < (unsigned)WW);
        const bool okx1 = ((unsigned)(ix + 1) < (unsigned)WW);
        const bool oky0 = ((unsigned)iy       < (unsigned)HH);
        const bool oky1 = ((unsigned)(iy + 1) < (unsigned)HH);
        const float* row0 = img + iy * WW;
        const float* row1 = row0 + WW;
        const float v00 = (okx0 && oky0) ? row0[ix]     : 0.0f;
        const float v10 = (okx1 && oky0) ? row0[ix + 1] : 0.0f;
        const float v01 = (okx0 && oky1) ? row1[ix]     : 0.0f;
        const float v11 = (okx1 && oky1) ? row1[ix + 1] : 0.0f;
        const float gx0 = 1.0f - fx;
        const float gy0 = 1.0f - fy;
        sum += (v00 * gx0 + v10 * fx) * gy0 + (v01 * gx0 + v11 * fx) * fy;
    }

    __shared__ float red[16][17];
    red[dl][tph] = sum;
    __syncthreads();
    if (tid < 16) {
        float s = 0.0f;
#pragma unroll
        for (int k = 0; k < 16; ++k) s += red[tid][k];
        const int od = (b * VV + v) * DD + (dblk << 4) + tid;
        temp[od] = fmaf(F_DT, s, -proj[od]);
    }
}

// ---------------------------------------------------------------------------
// Kernel B: pixel-driven exact adjoint, view-segmented for occupancy.
// No bounds checks needed: pixel radius <= 0.99609*sqrt2 < sqrt2, so
// dc,tc in [0.499, 254.501] -> d0 in [0,254], d0+1 in [1,255] always.
// pacc[seg][pixel] = sum over this segment's views.
// ---------------------------------------------------------------------------
__global__ __launch_bounds__(256)
void bwd_partial_kernel(const float* __restrict__ temp,
                        float* __restrict__ pacc,
                        int nv, int npix) {
    __shared__ float4 s_g[VV];
    const int tid = threadIdx.x;
    const int v0 = blockIdx.y * nv;
    if (tid < nv) {
        float sn, cs;
        sincosf(view_angle(v0 + tid), &sn, &cs);
        s_g[tid] = make_float4(cs, sn, F_SIG * cs, F_SIG * sn);
    }
    __syncthreads();

    const int idx = blockIdx.x * 256 + tid;
    const int b = idx >> 16;            // H*W = 65536 pixels per image
    const int y = (idx >> 8) & 255;
    const int x = idx & 255;
    const float* __restrict__ tb = temp + b * (VV * DD) + v0 * DD;

    const float xw = (x + 0.5f) * (1.0f / 128.0f) - 1.0f;
    const float yw = (y + 0.5f) * (1.0f / 128.0f) - 1.0f;

    float acc = 0.0f;
    for (int vi = 0; vi < nv; ++vi) {
        const float4 g = s_g[vi];       // cs, sn, A=sig*cs, B=sig*sn
        const float sw = fmaf(-xw, g.y, yw * g.x);
        const float tw = fmaf( xw, g.x, yw * g.y);
        const float dc = fmaf(sw, F_INV_DS, 127.5f);   // (sw+sq2)*inv_ds
        const float tc = fmaf(tw, F_INV_DS, 127.5f);
        const float d0f = floorf(dc);
        const float t0f = floorf(tc);
        const int d0 = (int)d0f;
        const float fd = dc - d0f;
        const float ft = tc - t0f;

        // pixel-space offsets of the 4 neighbor samples; signs irrelevant (abs)
        const float dx00 = fmaf(g.z, -ft, g.w * fd);   // A*dt0 - B*dd0
        const float dyn  = fmaf(g.z,  fd, g.w * ft);   // -(A*dd0 + B*dt0)
        const float dx01 = dx00 + g.z;
        const float dy01 = g.w - dyn;
        const float dx10 = dx00 - g.w;
        const float dy10 = g.z - dyn;
        const float dx11 = dx01 - g.w;
        const float dy11 = dy10 + g.w;

        const float w00 = fmaxf(0.0f, 1.0f - fabsf(dx00)) * fmaxf(0.0f, 1.0f - fabsf(dyn));
        const float w01 = fmaxf(0.0f, 1.0f - fabsf(dx01)) * fmaxf(0.0f, 1.0f - fabsf(dy01));
        const float w10 = fmaxf(0.0f, 1.0f - fabsf(dx10)) * fmaxf(0.0f, 1.0f - fabsf(dy10));
        const float w11 = fmaxf(0.0f, 1.0f - fabsf(dx11)) * fmaxf(0.0f, 1.0f - fabsf(dy11));

        const float* r = tb + vi * DD + d0;
        acc = fmaf(w00 + w01, r[0], acc);
        acc = fmaf(w10 + w11, r[1], acc);
    }

    pacc[blockIdx.y * npix + idx] = acc;
}

// out = input - weight*DT*sum_seg pacc  (float4 vectorized)
__global__ __launch_bounds__(256)
void combine_kernel(const float* __restrict__ input,
                    const float* __restrict__ pacc,
                    const float* __restrict__ weight,
                    float* __restrict__ out,
                    int nseg, int npix) {
    const int i = blockIdx.x * 256 + threadIdx.x;      // float4 index
    const float4* __restrict__ in4 = (const float4*)input;
    float4* __restrict__ out4 = (float4*)out;
    float4 a = make_float4(0.f, 0.f, 0.f, 0.f);
    for (int s = 0; s < nseg; ++s) {
        const float4 p = ((const float4*)(pacc + (size_t)s * npix))[i];
        a.x += p.x; a.y += p.y; a.z += p.z; a.w += p.w;
    }
    const float c = -weight[0] * F_DT;
    const float4 v = in4[i];
    out4[i] = make_float4(fmaf(c, a.x, v.x), fmaf(c, a.y, v.y),
                          fmaf(c, a.z, v.z), fmaf(c, a.w, v.w));
}

extern "C" void kernel_launch(void* const* d_in, const int* in_sizes, int n_in,
                              void* d_out, int out_size, void* d_ws, size_t ws_size,
                              hipStream_t stream) {
    const float* input  = (const float*)d_in[0];   // [nb, H, W]
    const float* proj   = (const float*)d_in[1];   // [nb, V, D]
    const float* weight = (const float*)d_in[2];   // [1]
    float* out  = (float*)d_out;                   // [nb, H, W]
    float* temp = (float*)d_ws;                    // [nb, V, D] residual sinogram

    const int nb = in_sizes[0] / (HH * WW);        // B*C = 2
    const int npix = nb * HH * WW;
    const size_t temp_bytes = (size_t)nb * VV * DD * sizeof(float);
    float* pacc = (float*)((char*)d_ws + temp_bytes);

    // pick the largest view-segmentation that fits the workspace
    int nseg = 4;
    while (nseg > 1 && temp_bytes + (size_t)nseg * npix * sizeof(float) > ws_size)
        nseg >>= 1;
    const int nv = VV / nseg;

    fwd_residual_kernel<<<dim3(16, VV, nb), 256, 0, stream>>>(input, proj, temp);
    bwd_partial_kernel<<<dim3(npix / 256, nseg), 256, 0, stream>>>(temp, pacc, nv, npix);
    combine_kernel<<<npix / 1024, 256, 0, stream>>>(input, pacc, weight, out, nseg, npix);
}